// Round 2
// baseline (1243.127 us; speedup 1.0000x reference)
//
#include <hip/hip_runtime.h>
#include <hip/hip_bf16.h>

// ---------------- CSR build ----------------

__global__ void count_deg_kernel(const int* __restrict__ dst, int* __restrict__ deg, int E) {
    int e = blockIdx.x * blockDim.x + threadIdx.x;
    if (e < E) atomicAdd(&deg[dst[e]], 1);
}

__global__ __launch_bounds__(1024) void scan_deg_kernel(const int* __restrict__ deg,
                                                        int* __restrict__ offsets,
                                                        int* __restrict__ cursor, int n) {
    __shared__ int sums[1024];
    int tid = threadIdx.x;
    int chunk = (n + 1023) >> 10;
    int s0 = tid * chunk;
    int s1 = min(s0 + chunk, n);
    int local = 0;
    for (int i = s0; i < s1; ++i) local += deg[i];
    sums[tid] = local;
    __syncthreads();
    // Hillis-Steele inclusive scan over the 1024 partial sums
    for (int off = 1; off < 1024; off <<= 1) {
        int v = (tid >= off) ? sums[tid - off] : 0;
        __syncthreads();
        sums[tid] += v;
        __syncthreads();
    }
    int run = (tid == 0) ? 0 : sums[tid - 1];
    for (int i = s0; i < s1; ++i) {
        offsets[i] = run;
        cursor[i]  = run;
        run += deg[i];
    }
    if (tid == 1023) offsets[n] = sums[1023];
}

__global__ void scatter_edges_kernel(const int* __restrict__ src, const int* __restrict__ dst,
                                     int* __restrict__ cursor, int* __restrict__ csr_src, int E) {
    int e = blockIdx.x * blockDim.x + threadIdx.x;
    if (e < E) {
        int d = dst[e];
        int pos = atomicAdd(&cursor[d], 1);
        csr_src[pos] = src[e];
    }
}

// ---------------- Fused conv layer: mean-aggregate + residual + linear + relu ----------------
// One block (128 threads) per node. F_IN, F_OUT <= 128.

template <int F_IN, int F_OUT>
__global__ __launch_bounds__(128) void conv_kernel(const float* __restrict__ x,
                                                   const int* __restrict__ offsets,
                                                   const int* __restrict__ csr_src,
                                                   const float* __restrict__ W,
                                                   const float* __restrict__ b,
                                                   float* __restrict__ y, int n) {
    int node = blockIdx.x;
    if (node >= n) return;
    int tid = threadIdx.x;
    __shared__ float h[F_IN];

    int start = offsets[node];
    int end   = offsets[node + 1];

    if (tid < F_IN) {
        float s = 0.0f;
        for (int e = start; e < end; ++e) {
            int nbr = csr_src[e];
            s += x[(size_t)nbr * F_IN + tid];
        }
        float d = fmaxf((float)(end - start), 1.0f);
        h[tid] = s / d + x[(size_t)node * F_IN + tid];
    }
    __syncthreads();

    if (tid < F_OUT) {
        const float* wrow = W + (size_t)tid * F_IN;
        float a0 = 0.f, a1 = 0.f, a2 = 0.f, a3 = 0.f;
#pragma unroll
        for (int f = 0; f < F_IN; f += 4) {
            a0 += wrow[f + 0] * h[f + 0];
            a1 += wrow[f + 1] * h[f + 1];
            a2 += wrow[f + 2] * h[f + 2];
            a3 += wrow[f + 3] * h[f + 3];
        }
        float acc = a0 + a1 + a2 + a3 + b[tid];
        y[(size_t)node * F_OUT + tid] = fmaxf(acc, 0.0f);
    }
}

// ---------------- Heads: next_event (64) + event_classes (10) from embeddings ----------------

__global__ __launch_bounds__(128) void head_kernel(const float* __restrict__ x,
                                                   const float* __restrict__ Wp, const float* __restrict__ bp,
                                                   const float* __restrict__ Wc, const float* __restrict__ bc,
                                                   float* __restrict__ nev, float* __restrict__ cls, int n) {
    int node = blockIdx.x;
    if (node >= n) return;
    int tid = threadIdx.x;
    __shared__ float h[64];
    if (tid < 64) h[tid] = x[(size_t)node * 64 + tid];
    __syncthreads();

    if (tid < 64) {
        const float* wrow = Wp + (size_t)tid * 64;
        float a0 = 0.f, a1 = 0.f, a2 = 0.f, a3 = 0.f;
#pragma unroll
        for (int f = 0; f < 64; f += 4) {
            a0 += wrow[f + 0] * h[f + 0];
            a1 += wrow[f + 1] * h[f + 1];
            a2 += wrow[f + 2] * h[f + 2];
            a3 += wrow[f + 3] * h[f + 3];
        }
        nev[(size_t)node * 64 + tid] = a0 + a1 + a2 + a3 + bp[tid];
    } else if (tid < 64 + 10) {
        int k = tid - 64;
        const float* wrow = Wc + (size_t)k * 64;
        float a0 = 0.f, a1 = 0.f, a2 = 0.f, a3 = 0.f;
#pragma unroll
        for (int f = 0; f < 64; f += 4) {
            a0 += wrow[f + 0] * h[f + 0];
            a1 += wrow[f + 1] * h[f + 1];
            a2 += wrow[f + 2] * h[f + 2];
            a3 += wrow[f + 3] * h[f + 3];
        }
        cls[(size_t)node * 10 + k] = a0 + a1 + a2 + a3 + bc[k];
    }
}

// ---------------- launch ----------------

extern "C" void kernel_launch(void* const* d_in, const int* in_sizes, int n_in,
                              void* d_out, int out_size, void* d_ws, size_t ws_size,
                              hipStream_t stream) {
    const float* x  = (const float*)d_in[0];
    const int*   ei = (const int*)d_in[1];
    const float* W1 = (const float*)d_in[2];
    const float* b1 = (const float*)d_in[3];
    const float* W2 = (const float*)d_in[4];
    const float* b2 = (const float*)d_in[5];
    const float* W3 = (const float*)d_in[6];
    const float* b3 = (const float*)d_in[7];
    const float* Wp = (const float*)d_in[8];
    const float* bp = (const float*)d_in[9];
    const float* Wc = (const float*)d_in[10];
    const float* bc = (const float*)d_in[11];

    const int n = in_sizes[0] / 64;   // 50000
    const int E = in_sizes[1] / 2;    // 800000
    const int* src = ei;
    const int* dst = ei + E;

    // workspace layout (ints then floats)
    int* deg     = (int*)d_ws;            // n
    int* offsets = deg + n;               // n+1
    int* cursor  = offsets + (n + 1);     // n
    int* csr_src = cursor + n;            // E
    float* xbuf1 = (float*)(csr_src + E); // n*128
    float* xbuf2 = xbuf1 + (size_t)n * 128;

    float* out_emb = (float*)d_out;                     // n*64
    float* out_nev = out_emb + (size_t)n * 64;          // n*64
    float* out_cls = out_nev + (size_t)n * 64;          // n*10

    hipMemsetAsync(deg, 0, (size_t)n * sizeof(int), stream);

    const int TB = 256;
    count_deg_kernel<<<(E + TB - 1) / TB, TB, 0, stream>>>(dst, deg, E);
    scan_deg_kernel<<<1, 1024, 0, stream>>>(deg, offsets, cursor, n);
    scatter_edges_kernel<<<(E + TB - 1) / TB, TB, 0, stream>>>(src, dst, cursor, csr_src, E);

    conv_kernel<64, 128><<<n, 128, 0, stream>>>(x,     offsets, csr_src, W1, b1, xbuf1,  n);
    conv_kernel<128, 128><<<n, 128, 0, stream>>>(xbuf1, offsets, csr_src, W2, b2, xbuf2,  n);
    conv_kernel<128, 64><<<n, 128, 0, stream>>>(xbuf2, offsets, csr_src, W3, b3, out_emb, n);

    head_kernel<<<n, 128, 0, stream>>>(out_emb, Wp, bp, Wc, bc, out_nev, out_cls, n);
}

// Round 3
// 529.513 us; speedup vs baseline: 2.3477x; 2.3477x over previous
//
#include <hip/hip_runtime.h>
#include <hip/hip_bf16.h>

// ---------------- CSR build ----------------

__global__ void count_deg_kernel(const int* __restrict__ dst, int* __restrict__ deg, int E) {
    int e = blockIdx.x * blockDim.x + threadIdx.x;
    if (e < E) atomicAdd(&deg[dst[e]], 1);
}

__global__ __launch_bounds__(1024) void scan_deg_kernel(const int* __restrict__ deg,
                                                        int* __restrict__ offsets,
                                                        int* __restrict__ cursor, int n) {
    __shared__ int sums[1024];
    int tid = threadIdx.x;
    int chunk = (n + 1023) >> 10;
    int s0 = tid * chunk;
    int s1 = min(s0 + chunk, n);
    int local = 0;
    for (int i = s0; i < s1; ++i) local += deg[i];
    sums[tid] = local;
    __syncthreads();
    for (int off = 1; off < 1024; off <<= 1) {
        int v = (tid >= off) ? sums[tid - off] : 0;
        __syncthreads();
        sums[tid] += v;
        __syncthreads();
    }
    int run = (tid == 0) ? 0 : sums[tid - 1];
    for (int i = s0; i < s1; ++i) {
        offsets[i] = run;
        cursor[i]  = run;
        run += deg[i];
    }
    if (tid == 1023) offsets[n] = sums[1023];
}

__global__ void scatter_edges_kernel(const int* __restrict__ src, const int* __restrict__ dst,
                                     int* __restrict__ cursor, int* __restrict__ csr_src, int E) {
    int e = blockIdx.x * blockDim.x + threadIdx.x;
    if (e < E) {
        int d = dst[e];
        int pos = atomicAdd(&cursor[d], 1);
        csr_src[pos] = src[e];
    }
}

// ---------------- Aggregation: h = mean-neighbor(x) + x ----------------
// One 64-lane wave per node; 4 nodes per 256-thread block. Lanes cooperatively
// load up to 64 neighbor indices (coalesced), broadcast with __shfl, and the
// wave reads each neighbor's full row in one vector load (float2/lane @ F=128).

template <int F>
__global__ __launch_bounds__(256) void agg_kernel(const float* __restrict__ x,
                                                  const int* __restrict__ offsets,
                                                  const int* __restrict__ csr_src,
                                                  float* __restrict__ h, int n) {
    const int lane = threadIdx.x & 63;
    const int node = blockIdx.x * 4 + (threadIdx.x >> 6);
    if (node >= n) return;
    const int start = offsets[node];
    const int end   = offsets[node + 1];

    float s0 = 0.f, s1 = 0.f;
    int e = start;
    while (e < end) {
        int cnt = min(64, end - e);
        int ii = e + lane; if (ii >= end) ii = end - 1;
        int idx = csr_src[ii];
        int j = 0;
        for (; j + 4 <= cnt; j += 4) {
            int n0 = __shfl(idx, j,     64);
            int n1 = __shfl(idx, j + 1, 64);
            int n2 = __shfl(idx, j + 2, 64);
            int n3 = __shfl(idx, j + 3, 64);
            if (F == 128) {
                float2 v0 = *(const float2*)&x[(size_t)n0 * F + lane * 2];
                float2 v1 = *(const float2*)&x[(size_t)n1 * F + lane * 2];
                float2 v2 = *(const float2*)&x[(size_t)n2 * F + lane * 2];
                float2 v3 = *(const float2*)&x[(size_t)n3 * F + lane * 2];
                s0 += v0.x + v1.x + v2.x + v3.x;
                s1 += v0.y + v1.y + v2.y + v3.y;
            } else {
                s0 += x[(size_t)n0 * F + lane] + x[(size_t)n1 * F + lane]
                    + x[(size_t)n2 * F + lane] + x[(size_t)n3 * F + lane];
            }
        }
        for (; j < cnt; ++j) {
            int nb = __shfl(idx, j, 64);
            if (F == 128) {
                float2 v = *(const float2*)&x[(size_t)nb * F + lane * 2];
                s0 += v.x; s1 += v.y;
            } else {
                s0 += x[(size_t)nb * F + lane];
            }
        }
        e += cnt;
    }

    float inv = 1.0f / fmaxf((float)(end - start), 1.0f);
    if (F == 128) {
        float2 xr = *(const float2*)&x[(size_t)node * F + lane * 2];
        float2 o;
        o.x = s0 * inv + xr.x;
        o.y = s1 * inv + xr.y;
        *(float2*)&h[(size_t)node * F + lane * 2] = o;
    } else {
        h[(size_t)node * F + lane] = s0 * inv + x[(size_t)node * F + lane];
    }
}

// ---------------- Tiled GEMM: Y = act(H @ W^T + b) ----------------
// 64 nodes x F_OUT per 256-thread block. W k-chunk + H tile staged in LDS
// (PAD=68 keeps float4 alignment; <=2-way bank conflicts which are free).

template <int F_IN, int F_OUT, bool RELU>
__global__ __launch_bounds__(256) void gemm_kernel(const float* __restrict__ H,
                                                   const float* __restrict__ W,
                                                   const float* __restrict__ bias,
                                                   float* __restrict__ Y, int n) {
    constexpr int BK = 64, PAD = 68, MT = 64;
    constexpr int OJ = F_OUT / 16;
    __shared__ float Ws[F_OUT * PAD];
    __shared__ float Hs[MT * PAD];

    const int tid = threadIdx.x;
    const int tx = tid & 15, ty = tid >> 4;   // 16 x 16
    const int m0 = blockIdx.x * MT;
    const int mcnt = min(MT, n - m0);

    float acc[4][OJ];
#pragma unroll
    for (int i = 0; i < 4; ++i)
#pragma unroll
        for (int j = 0; j < OJ; ++j) acc[i][j] = 0.f;

    const int rt = tid >> 4;          // staging: row group
    const int ct = (tid & 15) * 4;    // staging: float4 col within 64-wide chunk

    for (int kc = 0; kc < F_IN; kc += BK) {
        for (int r = rt; r < F_OUT; r += 16) {
            float4 v = *(const float4*)&W[(size_t)r * F_IN + kc + ct];
            *(float4*)&Ws[r * PAD + ct] = v;
        }
        for (int r = rt; r < MT; r += 16) {
            float4 v = make_float4(0.f, 0.f, 0.f, 0.f);
            if (r < mcnt) v = *(const float4*)&H[(size_t)(m0 + r) * F_IN + kc + ct];
            *(float4*)&Hs[r * PAD + ct] = v;
        }
        __syncthreads();

        for (int k = 0; k < BK; k += 4) {
            float4 hv[4], wv[OJ];
#pragma unroll
            for (int i = 0; i < 4; ++i) hv[i] = *(const float4*)&Hs[(ty + 16 * i) * PAD + k];
#pragma unroll
            for (int j = 0; j < OJ; ++j) wv[j] = *(const float4*)&Ws[(tx + 16 * j) * PAD + k];
#pragma unroll
            for (int i = 0; i < 4; ++i)
#pragma unroll
                for (int j = 0; j < OJ; ++j)
                    acc[i][j] += hv[i].x * wv[j].x + hv[i].y * wv[j].y
                               + hv[i].z * wv[j].z + hv[i].w * wv[j].w;
        }
        __syncthreads();
    }

#pragma unroll
    for (int i = 0; i < 4; ++i) {
        int m = ty + 16 * i;
        if (m < mcnt) {
#pragma unroll
            for (int j = 0; j < OJ; ++j) {
                int o = tx + 16 * j;
                float v = acc[i][j] + bias[o];
                if (RELU) v = fmaxf(v, 0.f);
                Y[(size_t)(m0 + m) * F_OUT + o] = v;
            }
        }
    }
}

// ---------------- Heads: nev = X@Wp^T+bp (64), cls = X@Wc^T+bc (10) ----------------

__global__ __launch_bounds__(256) void heads_kernel(const float* __restrict__ X,
                                                    const float* __restrict__ Wp, const float* __restrict__ bp,
                                                    const float* __restrict__ Wc, const float* __restrict__ bc,
                                                    float* __restrict__ nev, float* __restrict__ cls, int n) {
    constexpr int PAD = 68, MT = 64, OJ = 5;   // 80 output rows (74 real, 6 zero)
    __shared__ float Ws[80 * PAD];
    __shared__ float Hs[MT * PAD];

    const int tid = threadIdx.x;
    const int rt = tid >> 4;
    const int ct = (tid & 15) * 4;
    const int m0 = blockIdx.x * MT;
    const int mcnt = min(MT, n - m0);

    for (int r = rt; r < 80; r += 16) {
        float4 v = make_float4(0.f, 0.f, 0.f, 0.f);
        if (r < 64)      v = *(const float4*)&Wp[(size_t)r * 64 + ct];
        else if (r < 74) v = *(const float4*)&Wc[(size_t)(r - 64) * 64 + ct];
        *(float4*)&Ws[r * PAD + ct] = v;
    }
    for (int r = rt; r < MT; r += 16) {
        float4 v = make_float4(0.f, 0.f, 0.f, 0.f);
        if (r < mcnt) v = *(const float4*)&X[(size_t)(m0 + r) * 64 + ct];
        *(float4*)&Hs[r * PAD + ct] = v;
    }
    __syncthreads();

    const int tx = tid & 15, ty = tid >> 4;
    float acc[4][OJ];
#pragma unroll
    for (int i = 0; i < 4; ++i)
#pragma unroll
        for (int j = 0; j < OJ; ++j) acc[i][j] = 0.f;

    for (int k = 0; k < 64; k += 4) {
        float4 hv[4], wv[OJ];
#pragma unroll
        for (int i = 0; i < 4; ++i) hv[i] = *(const float4*)&Hs[(ty + 16 * i) * PAD + k];
#pragma unroll
        for (int j = 0; j < OJ; ++j) wv[j] = *(const float4*)&Ws[(tx + 16 * j) * PAD + k];
#pragma unroll
        for (int i = 0; i < 4; ++i)
#pragma unroll
            for (int j = 0; j < OJ; ++j)
                acc[i][j] += hv[i].x * wv[j].x + hv[i].y * wv[j].y
                           + hv[i].z * wv[j].z + hv[i].w * wv[j].w;
    }

#pragma unroll
    for (int i = 0; i < 4; ++i) {
        int m = ty + 16 * i;
        if (m < mcnt) {
#pragma unroll
            for (int j = 0; j < OJ; ++j) {
                int o = tx + 16 * j;
                if (o < 64) {
                    nev[(size_t)(m0 + m) * 64 + o] = acc[i][j] + bp[o];
                } else if (o < 74) {
                    cls[(size_t)(m0 + m) * 10 + (o - 64)] = acc[i][j] + bc[o - 64];
                }
            }
        }
    }
}

// ---------------- launch ----------------

extern "C" void kernel_launch(void* const* d_in, const int* in_sizes, int n_in,
                              void* d_out, int out_size, void* d_ws, size_t ws_size,
                              hipStream_t stream) {
    const float* x  = (const float*)d_in[0];
    const int*   ei = (const int*)d_in[1];
    const float* W1 = (const float*)d_in[2];
    const float* b1 = (const float*)d_in[3];
    const float* W2 = (const float*)d_in[4];
    const float* b2 = (const float*)d_in[5];
    const float* W3 = (const float*)d_in[6];
    const float* b3 = (const float*)d_in[7];
    const float* Wp = (const float*)d_in[8];
    const float* bp = (const float*)d_in[9];
    const float* Wc = (const float*)d_in[10];
    const float* bc = (const float*)d_in[11];

    const int n = in_sizes[0] / 64;   // 50000
    const int E = in_sizes[1] / 2;    // 800000
    const int* src = ei;
    const int* dst = ei + E;

    // workspace layout (align float buffers to 256 B for float4/float2 loads)
    int* deg     = (int*)d_ws;            // n
    int* offsets = deg + n;               // n+1
    int* cursor  = offsets + (n + 1);     // n
    int* csr_src = cursor + n;            // E
    uintptr_t p = (uintptr_t)(csr_src + E);
    p = (p + 255) & ~(uintptr_t)255;
    float* Hbuf = (float*)p;                       // n*128
    float* Ybuf = Hbuf + (size_t)n * 128;          // n*128

    float* out_emb = (float*)d_out;                // n*64
    float* out_nev = out_emb + (size_t)n * 64;     // n*64
    float* out_cls = out_nev + (size_t)n * 64;     // n*10

    hipMemsetAsync(deg, 0, (size_t)n * sizeof(int), stream);

    const int TB = 256;
    count_deg_kernel<<<(E + TB - 1) / TB, TB, 0, stream>>>(dst, deg, E);
    scan_deg_kernel<<<1, 1024, 0, stream>>>(deg, offsets, cursor, n);
    scatter_edges_kernel<<<(E + TB - 1) / TB, TB, 0, stream>>>(src, dst, cursor, csr_src, E);

    const int gAgg  = (n + 3) / 4;
    const int gGemm = (n + 63) / 64;

    agg_kernel<64><<<gAgg, 256, 0, stream>>>(x, offsets, csr_src, Hbuf, n);
    gemm_kernel<64, 128, true><<<gGemm, 256, 0, stream>>>(Hbuf, W1, b1, Ybuf, n);

    agg_kernel<128><<<gAgg, 256, 0, stream>>>(Ybuf, offsets, csr_src, Hbuf, n);
    gemm_kernel<128, 128, true><<<gGemm, 256, 0, stream>>>(Hbuf, W2, b2, Ybuf, n);

    agg_kernel<128><<<gAgg, 256, 0, stream>>>(Ybuf, offsets, csr_src, Hbuf, n);
    gemm_kernel<128, 64, true><<<gGemm, 256, 0, stream>>>(Hbuf, W3, b3, out_emb, n);

    heads_kernel<<<gGemm, 256, 0, stream>>>(out_emb, Wp, bp, Wc, bc, out_nev, out_cls, n);
}

// Round 4
// 431.101 us; speedup vs baseline: 2.8836x; 1.2283x over previous
//
#include <hip/hip_runtime.h>
#include <hip/hip_bf16.h>

// ---------------- CSR build ----------------

__global__ void count_deg_kernel(const int* __restrict__ dst, int* __restrict__ deg, int E) {
    int e = blockIdx.x * blockDim.x + threadIdx.x;
    if (e < E) atomicAdd(&deg[dst[e]], 1);
}

// Two-level scan, 256 elements per block.
__global__ __launch_bounds__(256) void partial_sum_kernel(const int* __restrict__ deg,
                                                          int* __restrict__ partial, int n) {
    __shared__ int s[256];
    int t = threadIdx.x;
    int i = blockIdx.x * 256 + t;
    s[t] = (i < n) ? deg[i] : 0;
    __syncthreads();
    for (int off = 128; off > 0; off >>= 1) {
        if (t < off) s[t] += s[t + off];
        __syncthreads();
    }
    if (t == 0) partial[blockIdx.x] = s[0];
}

// One block scans up to 256 partials -> exclusive block offsets; writes offsets[n]=total.
__global__ __launch_bounds__(256) void scan_partials_kernel(const int* __restrict__ partial,
                                                            int* __restrict__ blockoff,
                                                            int* __restrict__ offsets,
                                                            int nblocks, int n) {
    __shared__ int s[256];
    int t = threadIdx.x;
    int v = (t < nblocks) ? partial[t] : 0;
    s[t] = v;
    __syncthreads();
    for (int off = 1; off < 256; off <<= 1) {
        int u = (t >= off) ? s[t - off] : 0;
        __syncthreads();
        s[t] += u;
        __syncthreads();
    }
    if (t < nblocks) blockoff[t] = s[t] - v;   // exclusive
    if (t == nblocks - 1) offsets[n] = s[t];   // total
}

__global__ __launch_bounds__(256) void local_scan_kernel(const int* __restrict__ deg,
                                                         const int* __restrict__ blockoff,
                                                         int* __restrict__ offsets,
                                                         int* __restrict__ cursor, int n) {
    __shared__ int s[256];
    int t = threadIdx.x;
    int i = blockIdx.x * 256 + t;
    int v = (i < n) ? deg[i] : 0;
    s[t] = v;
    __syncthreads();
    for (int off = 1; off < 256; off <<= 1) {
        int u = (t >= off) ? s[t - off] : 0;
        __syncthreads();
        s[t] += u;
        __syncthreads();
    }
    if (i < n) {
        int o = blockoff[blockIdx.x] + s[t] - v;  // exclusive prefix
        offsets[i] = o;
        cursor[i]  = o;
    }
}

__global__ void scatter_edges_kernel(const int* __restrict__ src, const int* __restrict__ dst,
                                     int* __restrict__ cursor, int* __restrict__ csr_src, int E) {
    int e = blockIdx.x * blockDim.x + threadIdx.x;
    if (e < E) {
        int d = dst[e];
        int pos = atomicAdd(&cursor[d], 1);
        csr_src[pos] = src[e];
    }
}

// ---------------- Aggregation: h = mean-neighbor(x) + x ----------------
// One 64-lane wave per node; 4 nodes per 256-thread block. Lanes cooperatively
// load up to 64 neighbor indices (coalesced), broadcast with __shfl, and the
// wave reads each neighbor's full row in one vector load (float2/lane @ F=128).

template <int F>
__global__ __launch_bounds__(256) void agg_kernel(const float* __restrict__ x,
                                                  const int* __restrict__ offsets,
                                                  const int* __restrict__ csr_src,
                                                  float* __restrict__ h, int n) {
    const int lane = threadIdx.x & 63;
    const int node = blockIdx.x * 4 + (threadIdx.x >> 6);
    if (node >= n) return;
    const int start = offsets[node];
    const int end   = offsets[node + 1];

    float s0 = 0.f, s1 = 0.f;
    int e = start;
    while (e < end) {
        int cnt = min(64, end - e);
        int ii = e + lane; if (ii >= end) ii = end - 1;
        int idx = csr_src[ii];
        int j = 0;
        for (; j + 4 <= cnt; j += 4) {
            int n0 = __shfl(idx, j,     64);
            int n1 = __shfl(idx, j + 1, 64);
            int n2 = __shfl(idx, j + 2, 64);
            int n3 = __shfl(idx, j + 3, 64);
            if (F == 128) {
                float2 v0 = *(const float2*)&x[(size_t)n0 * F + lane * 2];
                float2 v1 = *(const float2*)&x[(size_t)n1 * F + lane * 2];
                float2 v2 = *(const float2*)&x[(size_t)n2 * F + lane * 2];
                float2 v3 = *(const float2*)&x[(size_t)n3 * F + lane * 2];
                s0 += v0.x + v1.x + v2.x + v3.x;
                s1 += v0.y + v1.y + v2.y + v3.y;
            } else {
                s0 += x[(size_t)n0 * F + lane] + x[(size_t)n1 * F + lane]
                    + x[(size_t)n2 * F + lane] + x[(size_t)n3 * F + lane];
            }
        }
        for (; j < cnt; ++j) {
            int nb = __shfl(idx, j, 64);
            if (F == 128) {
                float2 v = *(const float2*)&x[(size_t)nb * F + lane * 2];
                s0 += v.x; s1 += v.y;
            } else {
                s0 += x[(size_t)nb * F + lane];
            }
        }
        e += cnt;
    }

    float inv = 1.0f / fmaxf((float)(end - start), 1.0f);
    if (F == 128) {
        float2 xr = *(const float2*)&x[(size_t)node * F + lane * 2];
        float2 o;
        o.x = s0 * inv + xr.x;
        o.y = s1 * inv + xr.y;
        *(float2*)&h[(size_t)node * F + lane * 2] = o;
    } else {
        h[(size_t)node * F + lane] = s0 * inv + x[(size_t)node * F + lane];
    }
}

// ---------------- Tiled GEMM: Y = act(H @ W^T + b) ----------------

template <int F_IN, int F_OUT, bool RELU>
__global__ __launch_bounds__(256) void gemm_kernel(const float* __restrict__ H,
                                                   const float* __restrict__ W,
                                                   const float* __restrict__ bias,
                                                   float* __restrict__ Y, int n) {
    constexpr int BK = 64, PAD = 68, MT = 64;
    constexpr int OJ = F_OUT / 16;
    __shared__ float Ws[F_OUT * PAD];
    __shared__ float Hs[MT * PAD];

    const int tid = threadIdx.x;
    const int tx = tid & 15, ty = tid >> 4;   // 16 x 16
    const int m0 = blockIdx.x * MT;
    const int mcnt = min(MT, n - m0);

    float acc[4][OJ];
#pragma unroll
    for (int i = 0; i < 4; ++i)
#pragma unroll
        for (int j = 0; j < OJ; ++j) acc[i][j] = 0.f;

    const int rt = tid >> 4;
    const int ct = (tid & 15) * 4;

    for (int kc = 0; kc < F_IN; kc += BK) {
        for (int r = rt; r < F_OUT; r += 16) {
            float4 v = *(const float4*)&W[(size_t)r * F_IN + kc + ct];
            *(float4*)&Ws[r * PAD + ct] = v;
        }
        for (int r = rt; r < MT; r += 16) {
            float4 v = make_float4(0.f, 0.f, 0.f, 0.f);
            if (r < mcnt) v = *(const float4*)&H[(size_t)(m0 + r) * F_IN + kc + ct];
            *(float4*)&Hs[r * PAD + ct] = v;
        }
        __syncthreads();

        for (int k = 0; k < BK; k += 4) {
            float4 hv[4], wv[OJ];
#pragma unroll
            for (int i = 0; i < 4; ++i) hv[i] = *(const float4*)&Hs[(ty + 16 * i) * PAD + k];
#pragma unroll
            for (int j = 0; j < OJ; ++j) wv[j] = *(const float4*)&Ws[(tx + 16 * j) * PAD + k];
#pragma unroll
            for (int i = 0; i < 4; ++i)
#pragma unroll
                for (int j = 0; j < OJ; ++j)
                    acc[i][j] += hv[i].x * wv[j].x + hv[i].y * wv[j].y
                               + hv[i].z * wv[j].z + hv[i].w * wv[j].w;
        }
        __syncthreads();
    }

#pragma unroll
    for (int i = 0; i < 4; ++i) {
        int m = ty + 16 * i;
        if (m < mcnt) {
#pragma unroll
            for (int j = 0; j < OJ; ++j) {
                int o = tx + 16 * j;
                float v = acc[i][j] + bias[o];
                if (RELU) v = fmaxf(v, 0.f);
                Y[(size_t)(m0 + m) * F_OUT + o] = v;
            }
        }
    }
}

// ---------------- Heads: nev = X@Wp^T+bp (64), cls = X@Wc^T+bc (10) ----------------

__global__ __launch_bounds__(256) void heads_kernel(const float* __restrict__ X,
                                                    const float* __restrict__ Wp, const float* __restrict__ bp,
                                                    const float* __restrict__ Wc, const float* __restrict__ bc,
                                                    float* __restrict__ nev, float* __restrict__ cls, int n) {
    constexpr int PAD = 68, MT = 64, OJ = 5;   // 80 output rows (74 real, 6 zero)
    __shared__ float Ws[80 * PAD];
    __shared__ float Hs[MT * PAD];

    const int tid = threadIdx.x;
    const int rt = tid >> 4;
    const int ct = (tid & 15) * 4;
    const int m0 = blockIdx.x * MT;
    const int mcnt = min(MT, n - m0);

    for (int r = rt; r < 80; r += 16) {
        float4 v = make_float4(0.f, 0.f, 0.f, 0.f);
        if (r < 64)      v = *(const float4*)&Wp[(size_t)r * 64 + ct];
        else if (r < 74) v = *(const float4*)&Wc[(size_t)(r - 64) * 64 + ct];
        *(float4*)&Ws[r * PAD + ct] = v;
    }
    for (int r = rt; r < MT; r += 16) {
        float4 v = make_float4(0.f, 0.f, 0.f, 0.f);
        if (r < mcnt) v = *(const float4*)&X[(size_t)(m0 + r) * 64 + ct];
        *(float4*)&Hs[r * PAD + ct] = v;
    }
    __syncthreads();

    const int tx = tid & 15, ty = tid >> 4;
    float acc[4][OJ];
#pragma unroll
    for (int i = 0; i < 4; ++i)
#pragma unroll
        for (int j = 0; j < OJ; ++j) acc[i][j] = 0.f;

    for (int k = 0; k < 64; k += 4) {
        float4 hv[4], wv[OJ];
#pragma unroll
        for (int i = 0; i < 4; ++i) hv[i] = *(const float4*)&Hs[(ty + 16 * i) * PAD + k];
#pragma unroll
        for (int j = 0; j < OJ; ++j) wv[j] = *(const float4*)&Ws[(tx + 16 * j) * PAD + k];
#pragma unroll
        for (int i = 0; i < 4; ++i)
#pragma unroll
            for (int j = 0; j < OJ; ++j)
                acc[i][j] += hv[i].x * wv[j].x + hv[i].y * wv[j].y
                           + hv[i].z * wv[j].z + hv[i].w * wv[j].w;
    }

#pragma unroll
    for (int i = 0; i < 4; ++i) {
        int m = ty + 16 * i;
        if (m < mcnt) {
#pragma unroll
            for (int j = 0; j < OJ; ++j) {
                int o = tx + 16 * j;
                if (o < 64) {
                    nev[(size_t)(m0 + m) * 64 + o] = acc[i][j] + bp[o];
                } else if (o < 74) {
                    cls[(size_t)(m0 + m) * 10 + (o - 64)] = acc[i][j] + bc[o - 64];
                }
            }
        }
    }
}

// ---------------- launch ----------------

extern "C" void kernel_launch(void* const* d_in, const int* in_sizes, int n_in,
                              void* d_out, int out_size, void* d_ws, size_t ws_size,
                              hipStream_t stream) {
    const float* x  = (const float*)d_in[0];
    const int*   ei = (const int*)d_in[1];
    const float* W1 = (const float*)d_in[2];
    const float* b1 = (const float*)d_in[3];
    const float* W2 = (const float*)d_in[4];
    const float* b2 = (const float*)d_in[5];
    const float* W3 = (const float*)d_in[6];
    const float* b3 = (const float*)d_in[7];
    const float* Wp = (const float*)d_in[8];
    const float* bp = (const float*)d_in[9];
    const float* Wc = (const float*)d_in[10];
    const float* bc = (const float*)d_in[11];

    const int n = in_sizes[0] / 64;   // 50000
    const int E = in_sizes[1] / 2;    // 800000
    const int* src = ei;
    const int* dst = ei + E;

    const int nScanBlocks = (n + 255) / 256;   // 196

    // workspace layout
    int* deg      = (int*)d_ws;             // n
    int* offsets  = deg + n;                // n+1
    int* cursor   = offsets + (n + 1);      // n
    int* partial  = cursor + n;             // 256
    int* blockoff = partial + 256;          // 256
    int* csr_src  = blockoff + 256;         // E
    uintptr_t p = (uintptr_t)(csr_src + E);
    p = (p + 255) & ~(uintptr_t)255;
    float* Hbuf = (float*)p;                       // n*128
    float* Ybuf = Hbuf + (size_t)n * 128;          // n*128

    float* out_emb = (float*)d_out;                // n*64
    float* out_nev = out_emb + (size_t)n * 64;     // n*64
    float* out_cls = out_nev + (size_t)n * 64;     // n*10

    hipMemsetAsync(deg, 0, (size_t)n * sizeof(int), stream);

    const int TB = 256;
    count_deg_kernel<<<(E + TB - 1) / TB, TB, 0, stream>>>(dst, deg, E);
    partial_sum_kernel<<<nScanBlocks, 256, 0, stream>>>(deg, partial, n);
    scan_partials_kernel<<<1, 256, 0, stream>>>(partial, blockoff, offsets, nScanBlocks, n);
    local_scan_kernel<<<nScanBlocks, 256, 0, stream>>>(deg, blockoff, offsets, cursor, n);
    scatter_edges_kernel<<<(E + TB - 1) / TB, TB, 0, stream>>>(src, dst, cursor, csr_src, E);

    const int gAgg  = (n + 3) / 4;
    const int gGemm = (n + 63) / 64;

    agg_kernel<64><<<gAgg, 256, 0, stream>>>(x, offsets, csr_src, Hbuf, n);
    gemm_kernel<64, 128, true><<<gGemm, 256, 0, stream>>>(Hbuf, W1, b1, Ybuf, n);

    agg_kernel<128><<<gAgg, 256, 0, stream>>>(Ybuf, offsets, csr_src, Hbuf, n);
    gemm_kernel<128, 128, true><<<gGemm, 256, 0, stream>>>(Hbuf, W2, b2, Ybuf, n);

    agg_kernel<128><<<gAgg, 256, 0, stream>>>(Ybuf, offsets, csr_src, Hbuf, n);
    gemm_kernel<128, 64, true><<<gGemm, 256, 0, stream>>>(Hbuf, W3, b3, out_emb, n);

    heads_kernel<<<gGemm, 256, 0, stream>>>(out_emb, Wp, bp, Wc, bc, out_nev, out_cls, n);
}

// Round 5
// 380.612 us; speedup vs baseline: 3.2661x; 1.1327x over previous
//
#include <hip/hip_runtime.h>
#include <hip/hip_bf16.h>

typedef __hip_bfloat16 bf16;

// ---------------- CSR build ----------------

__global__ void count_deg_kernel(const int* __restrict__ dst, int* __restrict__ deg, int E) {
    int e = blockIdx.x * blockDim.x + threadIdx.x;
    if (e < E) atomicAdd(&deg[dst[e]], 1);
}

// Two-level scan, 256 elements per block.
__global__ __launch_bounds__(256) void partial_sum_kernel(const int* __restrict__ deg,
                                                          int* __restrict__ partial, int n) {
    __shared__ int s[256];
    int t = threadIdx.x;
    int i = blockIdx.x * 256 + t;
    s[t] = (i < n) ? deg[i] : 0;
    __syncthreads();
    for (int off = 128; off > 0; off >>= 1) {
        if (t < off) s[t] += s[t + off];
        __syncthreads();
    }
    if (t == 0) partial[blockIdx.x] = s[0];
}

__global__ __launch_bounds__(256) void scan_partials_kernel(const int* __restrict__ partial,
                                                            int* __restrict__ blockoff,
                                                            int* __restrict__ offsets,
                                                            int nblocks, int n) {
    __shared__ int s[256];
    int t = threadIdx.x;
    int v = (t < nblocks) ? partial[t] : 0;
    s[t] = v;
    __syncthreads();
    for (int off = 1; off < 256; off <<= 1) {
        int u = (t >= off) ? s[t - off] : 0;
        __syncthreads();
        s[t] += u;
        __syncthreads();
    }
    if (t < nblocks) blockoff[t] = s[t] - v;   // exclusive
    if (t == nblocks - 1) offsets[n] = s[t];   // total
}

__global__ __launch_bounds__(256) void local_scan_kernel(const int* __restrict__ deg,
                                                         const int* __restrict__ blockoff,
                                                         int* __restrict__ offsets,
                                                         int* __restrict__ cursor, int n) {
    __shared__ int s[256];
    int t = threadIdx.x;
    int i = blockIdx.x * 256 + t;
    int v = (i < n) ? deg[i] : 0;
    s[t] = v;
    __syncthreads();
    for (int off = 1; off < 256; off <<= 1) {
        int u = (t >= off) ? s[t - off] : 0;
        __syncthreads();
        s[t] += u;
        __syncthreads();
    }
    if (i < n) {
        int o = blockoff[blockIdx.x] + s[t] - v;  // exclusive prefix
        offsets[i] = o;
        cursor[i]  = o;
    }
}

__global__ void scatter_edges_kernel(const int* __restrict__ src, const int* __restrict__ dst,
                                     int* __restrict__ cursor, int* __restrict__ csr_src, int E) {
    int e = blockIdx.x * blockDim.x + threadIdx.x;
    if (e < E) {
        int d = dst[e];
        int pos = atomicAdd(&cursor[d], 1);
        csr_src[pos] = src[e];
    }
}

// ---------------- Aggregation (fp32 table, F=64): h = mean-neighbor(x) + x ----------------

__global__ __launch_bounds__(256) void agg_f32_64_kernel(const float* __restrict__ x,
                                                         const int* __restrict__ offsets,
                                                         const int* __restrict__ csr_src,
                                                         float* __restrict__ h, int n) {
    const int lane = threadIdx.x & 63;
    const int node = blockIdx.x * 4 + (threadIdx.x >> 6);
    if (node >= n) return;
    const int start = offsets[node];
    const int end   = offsets[node + 1];

    float s0 = 0.f;
    int e = start;
    while (e < end) {
        int cnt = min(64, end - e);
        int ii = e + lane; if (ii >= end) ii = end - 1;
        int idx = csr_src[ii];
        int j = 0;
        for (; j + 4 <= cnt; j += 4) {
            int n0 = __shfl(idx, j,     64);
            int n1 = __shfl(idx, j + 1, 64);
            int n2 = __shfl(idx, j + 2, 64);
            int n3 = __shfl(idx, j + 3, 64);
            s0 += x[(size_t)n0 * 64 + lane] + x[(size_t)n1 * 64 + lane]
                + x[(size_t)n2 * 64 + lane] + x[(size_t)n3 * 64 + lane];
        }
        for (; j < cnt; ++j) {
            int nb = __shfl(idx, j, 64);
            s0 += x[(size_t)nb * 64 + lane];
        }
        e += cnt;
    }

    float inv = 1.0f / fmaxf((float)(end - start), 1.0f);
    h[(size_t)node * 64 + lane] = s0 * inv + x[(size_t)node * 64 + lane];
}

// ---------------- Aggregation (bf16 table, F=128): h = mean-neighbor(yb) + yb ----------------
// One uint per lane = 2 bf16 = the full 256 B row per wave-load.

__device__ __forceinline__ float bf_lo(unsigned int u) { return __uint_as_float(u << 16); }
__device__ __forceinline__ float bf_hi(unsigned int u) { return __uint_as_float(u & 0xffff0000u); }

__global__ __launch_bounds__(256) void agg_bf16_128_kernel(const bf16* __restrict__ xb,
                                                           const int* __restrict__ offsets,
                                                           const int* __restrict__ csr_src,
                                                           float* __restrict__ h, int n) {
    const int lane = threadIdx.x & 63;
    const int node = blockIdx.x * 4 + (threadIdx.x >> 6);
    if (node >= n) return;
    const int start = offsets[node];
    const int end   = offsets[node + 1];
    const unsigned int* xt = (const unsigned int*)xb;   // row stride 64 uints

    float s0 = 0.f, s1 = 0.f;
    int e = start;
    while (e < end) {
        int cnt = min(64, end - e);
        int ii = e + lane; if (ii >= end) ii = end - 1;
        int idx = csr_src[ii];
        int j = 0;
        for (; j + 4 <= cnt; j += 4) {
            int n0 = __shfl(idx, j,     64);
            int n1 = __shfl(idx, j + 1, 64);
            int n2 = __shfl(idx, j + 2, 64);
            int n3 = __shfl(idx, j + 3, 64);
            unsigned int u0 = xt[(size_t)n0 * 64 + lane];
            unsigned int u1 = xt[(size_t)n1 * 64 + lane];
            unsigned int u2 = xt[(size_t)n2 * 64 + lane];
            unsigned int u3 = xt[(size_t)n3 * 64 + lane];
            s0 += bf_lo(u0) + bf_lo(u1) + bf_lo(u2) + bf_lo(u3);
            s1 += bf_hi(u0) + bf_hi(u1) + bf_hi(u2) + bf_hi(u3);
        }
        for (; j < cnt; ++j) {
            int nb = __shfl(idx, j, 64);
            unsigned int u = xt[(size_t)nb * 64 + lane];
            s0 += bf_lo(u); s1 += bf_hi(u);
        }
        e += cnt;
    }

    float inv = 1.0f / fmaxf((float)(end - start), 1.0f);
    unsigned int ur = xt[(size_t)node * 64 + lane];
    float2 o;
    o.x = s0 * inv + bf_lo(ur);
    o.y = s1 * inv + bf_hi(ur);
    *(float2*)&h[(size_t)node * 128 + lane * 2] = o;
}

// ---------------- Tiled GEMM: Y = act(H @ W^T + b), fp32 math, fp32 or bf16 out ----------------

template <int F_IN, int F_OUT, bool RELU, typename OUT_T>
__global__ __launch_bounds__(256) void gemm_kernel(const float* __restrict__ H,
                                                   const float* __restrict__ W,
                                                   const float* __restrict__ bias,
                                                   OUT_T* __restrict__ Y, int n) {
    constexpr int BK = 64, PAD = 68, MT = 64;
    constexpr int OJ = F_OUT / 16;
    __shared__ float Ws[F_OUT * PAD];
    __shared__ float Hs[MT * PAD];

    const int tid = threadIdx.x;
    const int tx = tid & 15, ty = tid >> 4;   // 16 x 16
    const int m0 = blockIdx.x * MT;
    const int mcnt = min(MT, n - m0);

    float acc[4][OJ];
#pragma unroll
    for (int i = 0; i < 4; ++i)
#pragma unroll
        for (int j = 0; j < OJ; ++j) acc[i][j] = 0.f;

    const int rt = tid >> 4;
    const int ct = (tid & 15) * 4;

    for (int kc = 0; kc < F_IN; kc += BK) {
        for (int r = rt; r < F_OUT; r += 16) {
            float4 v = *(const float4*)&W[(size_t)r * F_IN + kc + ct];
            *(float4*)&Ws[r * PAD + ct] = v;
        }
        for (int r = rt; r < MT; r += 16) {
            float4 v = make_float4(0.f, 0.f, 0.f, 0.f);
            if (r < mcnt) v = *(const float4*)&H[(size_t)(m0 + r) * F_IN + kc + ct];
            *(float4*)&Hs[r * PAD + ct] = v;
        }
        __syncthreads();

        for (int k = 0; k < BK; k += 4) {
            float4 hv[4], wv[OJ];
#pragma unroll
            for (int i = 0; i < 4; ++i) hv[i] = *(const float4*)&Hs[(ty + 16 * i) * PAD + k];
#pragma unroll
            for (int j = 0; j < OJ; ++j) wv[j] = *(const float4*)&Ws[(tx + 16 * j) * PAD + k];
#pragma unroll
            for (int i = 0; i < 4; ++i)
#pragma unroll
                for (int j = 0; j < OJ; ++j)
                    acc[i][j] += hv[i].x * wv[j].x + hv[i].y * wv[j].y
                               + hv[i].z * wv[j].z + hv[i].w * wv[j].w;
        }
        __syncthreads();
    }

#pragma unroll
    for (int i = 0; i < 4; ++i) {
        int m = ty + 16 * i;
        if (m < mcnt) {
#pragma unroll
            for (int j = 0; j < OJ; ++j) {
                int o = tx + 16 * j;
                float v = acc[i][j] + bias[o];
                if (RELU) v = fmaxf(v, 0.f);
                Y[(size_t)(m0 + m) * F_OUT + o] = (OUT_T)v;
            }
        }
    }
}

// ---------------- Heads: nev = X@Wp^T+bp (64), cls = X@Wc^T+bc (10) ----------------

__global__ __launch_bounds__(256) void heads_kernel(const float* __restrict__ X,
                                                    const float* __restrict__ Wp, const float* __restrict__ bp,
                                                    const float* __restrict__ Wc, const float* __restrict__ bc,
                                                    float* __restrict__ nev, float* __restrict__ cls, int n) {
    constexpr int PAD = 68, MT = 64, OJ = 5;   // 80 output rows (74 real, 6 zero)
    __shared__ float Ws[80 * PAD];
    __shared__ float Hs[MT * PAD];

    const int tid = threadIdx.x;
    const int rt = tid >> 4;
    const int ct = (tid & 15) * 4;
    const int m0 = blockIdx.x * MT;
    const int mcnt = min(MT, n - m0);

    for (int r = rt; r < 80; r += 16) {
        float4 v = make_float4(0.f, 0.f, 0.f, 0.f);
        if (r < 64)      v = *(const float4*)&Wp[(size_t)r * 64 + ct];
        else if (r < 74) v = *(const float4*)&Wc[(size_t)(r - 64) * 64 + ct];
        *(float4*)&Ws[r * PAD + ct] = v;
    }
    for (int r = rt; r < MT; r += 16) {
        float4 v = make_float4(0.f, 0.f, 0.f, 0.f);
        if (r < mcnt) v = *(const float4*)&X[(size_t)(m0 + r) * 64 + ct];
        *(float4*)&Hs[r * PAD + ct] = v;
    }
    __syncthreads();

    const int tx = tid & 15, ty = tid >> 4;
    float acc[4][OJ];
#pragma unroll
    for (int i = 0; i < 4; ++i)
#pragma unroll
        for (int j = 0; j < OJ; ++j) acc[i][j] = 0.f;

    for (int k = 0; k < 64; k += 4) {
        float4 hv[4], wv[OJ];
#pragma unroll
        for (int i = 0; i < 4; ++i) hv[i] = *(const float4*)&Hs[(ty + 16 * i) * PAD + k];
#pragma unroll
        for (int j = 0; j < OJ; ++j) wv[j] = *(const float4*)&Ws[(tx + 16 * j) * PAD + k];
#pragma unroll
        for (int i = 0; i < 4; ++i)
#pragma unroll
            for (int j = 0; j < OJ; ++j)
                acc[i][j] += hv[i].x * wv[j].x + hv[i].y * wv[j].y
                           + hv[i].z * wv[j].z + hv[i].w * wv[j].w;
    }

#pragma unroll
    for (int i = 0; i < 4; ++i) {
        int m = ty + 16 * i;
        if (m < mcnt) {
#pragma unroll
            for (int j = 0; j < OJ; ++j) {
                int o = tx + 16 * j;
                if (o < 64) {
                    nev[(size_t)(m0 + m) * 64 + o] = acc[i][j] + bp[o];
                } else if (o < 74) {
                    cls[(size_t)(m0 + m) * 10 + (o - 64)] = acc[i][j] + bc[o - 64];
                }
            }
        }
    }
}

// ---------------- launch ----------------

extern "C" void kernel_launch(void* const* d_in, const int* in_sizes, int n_in,
                              void* d_out, int out_size, void* d_ws, size_t ws_size,
                              hipStream_t stream) {
    const float* x  = (const float*)d_in[0];
    const int*   ei = (const int*)d_in[1];
    const float* W1 = (const float*)d_in[2];
    const float* b1 = (const float*)d_in[3];
    const float* W2 = (const float*)d_in[4];
    const float* b2 = (const float*)d_in[5];
    const float* W3 = (const float*)d_in[6];
    const float* b3 = (const float*)d_in[7];
    const float* Wp = (const float*)d_in[8];
    const float* bp = (const float*)d_in[9];
    const float* Wc = (const float*)d_in[10];
    const float* bc = (const float*)d_in[11];

    const int n = in_sizes[0] / 64;   // 50000
    const int E = in_sizes[1] / 2;    // 800000
    const int* src = ei;
    const int* dst = ei + E;

    const int nScanBlocks = (n + 255) / 256;   // 196

    // workspace layout
    int* deg      = (int*)d_ws;             // n
    int* offsets  = deg + n;                // n+1
    int* cursor   = offsets + (n + 1);      // n
    int* partial  = cursor + n;             // 256
    int* blockoff = partial + 256;          // 256
    int* csr_src  = blockoff + 256;         // E
    uintptr_t p = (uintptr_t)(csr_src + E);
    p = (p + 255) & ~(uintptr_t)255;
    float* Hbuf = (float*)p;                       // n*128 fp32 (agg out / gemm in)
    bf16*  Yb   = (bf16*)(Hbuf + (size_t)n * 128); // n*128 bf16 (gemm out / next gather table)

    float* out_emb = (float*)d_out;                // n*64
    float* out_nev = out_emb + (size_t)n * 64;     // n*64
    float* out_cls = out_nev + (size_t)n * 64;     // n*10

    hipMemsetAsync(deg, 0, (size_t)n * sizeof(int), stream);

    const int TB = 256;
    count_deg_kernel<<<(E + TB - 1) / TB, TB, 0, stream>>>(dst, deg, E);
    partial_sum_kernel<<<nScanBlocks, 256, 0, stream>>>(deg, partial, n);
    scan_partials_kernel<<<1, 256, 0, stream>>>(partial, blockoff, offsets, nScanBlocks, n);
    local_scan_kernel<<<nScanBlocks, 256, 0, stream>>>(deg, blockoff, offsets, cursor, n);
    scatter_edges_kernel<<<(E + TB - 1) / TB, TB, 0, stream>>>(src, dst, cursor, csr_src, E);

    const int gAgg  = (n + 3) / 4;
    const int gGemm = (n + 63) / 64;

    agg_f32_64_kernel<<<gAgg, 256, 0, stream>>>(x, offsets, csr_src, Hbuf, n);
    gemm_kernel<64, 128, true, bf16><<<gGemm, 256, 0, stream>>>(Hbuf, W1, b1, Yb, n);

    agg_bf16_128_kernel<<<gAgg, 256, 0, stream>>>(Yb, offsets, csr_src, Hbuf, n);
    gemm_kernel<128, 128, true, bf16><<<gGemm, 256, 0, stream>>>(Hbuf, W2, b2, Yb, n);

    agg_bf16_128_kernel<<<gAgg, 256, 0, stream>>>(Yb, offsets, csr_src, Hbuf, n);
    gemm_kernel<128, 64, true, float><<<gGemm, 256, 0, stream>>>(Hbuf, W3, b3, out_emb, n);

    heads_kernel<<<gGemm, 256, 0, stream>>>(out_emb, Wp, bp, Wc, bc, out_nev, out_cls, n);
}

// Round 6
// 369.865 us; speedup vs baseline: 3.3610x; 1.0291x over previous
//
#include <hip/hip_runtime.h>
#include <hip/hip_bf16.h>

typedef __hip_bfloat16 bf16;

__device__ __forceinline__ float bf_lo(unsigned int u) { return __uint_as_float(u << 16); }
__device__ __forceinline__ float bf_hi(unsigned int u) { return __uint_as_float(u & 0xffff0000u); }

__device__ __forceinline__ unsigned short f2bf_rne(float f) {
    unsigned u = __float_as_uint(f);
    unsigned rb = (u >> 16) & 1u;
    u += 0x7fffu + rb;
    return (unsigned short)(u >> 16);
}

// ---------------- x -> bf16 table ----------------

__global__ __launch_bounds__(256) void convert_x_kernel(const float* __restrict__ x,
                                                        unsigned int* __restrict__ xb, int total) {
    int i = blockIdx.x * blockDim.x + threadIdx.x;   // one uint = 2 floats
    if (i < total) {
        float2 f = ((const float2*)x)[i];
        xb[i] = (unsigned int)f2bf_rne(f.x) | ((unsigned int)f2bf_rne(f.y) << 16);
    }
}

// ---------------- CSR build (XCD-sharded by dst>>8 & 7) ----------------

__global__ __launch_bounds__(256) void count_deg_sharded_kernel(const int* __restrict__ dst,
                                                                int* __restrict__ deg, int E, int nSub) {
    const int shard = blockIdx.x & 7;
    const int sub   = blockIdx.x >> 3;
    const int per   = (E + nSub - 1) / nSub;
    const int lo = sub * per;
    const int hi = min(lo + per, E);
    for (int e = lo + threadIdx.x; e < hi; e += 256) {
        int d = dst[e];
        if (((d >> 8) & 7) == shard) atomicAdd(&deg[d], 1);
    }
}

__global__ __launch_bounds__(256) void scatter_sharded_kernel(const int* __restrict__ src,
                                                              const int* __restrict__ dst,
                                                              int* __restrict__ cursor,
                                                              int* __restrict__ csr_src, int E, int nSub) {
    const int shard = blockIdx.x & 7;
    const int sub   = blockIdx.x >> 3;
    const int per   = (E + nSub - 1) / nSub;
    const int lo = sub * per;
    const int hi = min(lo + per, E);
    for (int e = lo + threadIdx.x; e < hi; e += 256) {
        int d = dst[e];
        if (((d >> 8) & 7) == shard) {
            int s = src[e];
            int pos = atomicAdd(&cursor[d], 1);
            csr_src[pos] = s;
        }
    }
}

// Two-level scan, 256 elements per block.
__global__ __launch_bounds__(256) void partial_sum_kernel(const int* __restrict__ deg,
                                                          int* __restrict__ partial, int n) {
    __shared__ int s[256];
    int t = threadIdx.x;
    int i = blockIdx.x * 256 + t;
    s[t] = (i < n) ? deg[i] : 0;
    __syncthreads();
    for (int off = 128; off > 0; off >>= 1) {
        if (t < off) s[t] += s[t + off];
        __syncthreads();
    }
    if (t == 0) partial[blockIdx.x] = s[0];
}

__global__ __launch_bounds__(256) void scan_partials_kernel(const int* __restrict__ partial,
                                                            int* __restrict__ blockoff,
                                                            int* __restrict__ offsets,
                                                            int nblocks, int n) {
    __shared__ int s[256];
    int t = threadIdx.x;
    int v = (t < nblocks) ? partial[t] : 0;
    s[t] = v;
    __syncthreads();
    for (int off = 1; off < 256; off <<= 1) {
        int u = (t >= off) ? s[t - off] : 0;
        __syncthreads();
        s[t] += u;
        __syncthreads();
    }
    if (t < nblocks) blockoff[t] = s[t] - v;   // exclusive
    if (t == nblocks - 1) offsets[n] = s[t];   // total
}

__global__ __launch_bounds__(256) void local_scan_kernel(const int* __restrict__ deg,
                                                         const int* __restrict__ blockoff,
                                                         int* __restrict__ offsets,
                                                         int* __restrict__ cursor, int n) {
    __shared__ int s[256];
    int t = threadIdx.x;
    int i = blockIdx.x * 256 + t;
    int v = (i < n) ? deg[i] : 0;
    s[t] = v;
    __syncthreads();
    for (int off = 1; off < 256; off <<= 1) {
        int u = (t >= off) ? s[t - off] : 0;
        __syncthreads();
        s[t] += u;
        __syncthreads();
    }
    if (i < n) {
        int o = blockoff[blockIdx.x] + s[t] - v;  // exclusive prefix
        offsets[i] = o;
        cursor[i]  = o;
    }
}

// ---------------- Aggregation (bf16 table, F=64): h = mean-neighbor + self ----------------
// Wave per node; half-wave per neighbor (lanes 0-31: nbr j, 32-63: nbr j+1).

__global__ __launch_bounds__(256) void agg_bf16_64_kernel(const unsigned int* __restrict__ xt,
                                                          const int* __restrict__ offsets,
                                                          const int* __restrict__ csr_src,
                                                          float* __restrict__ h, int n) {
    const int lane = threadIdx.x & 63;
    const int node = blockIdx.x * 4 + (threadIdx.x >> 6);
    if (node >= n) return;
    const int half = lane >> 5;
    const int col  = lane & 31;          // uint column (2 features)
    const int start = offsets[node];
    const int end   = offsets[node + 1];

    float s0 = 0.f, s1 = 0.f;
    int e = start;
    while (e < end) {
        int cnt = min(64, end - e);
        int ii = e + lane; if (ii >= end) ii = end - 1;
        int idx = csr_src[ii];
        int j = 0;
        for (; j + 8 <= cnt; j += 8) {
            int a0 = __shfl(idx, j + 0, 64), a1 = __shfl(idx, j + 1, 64);
            int a2 = __shfl(idx, j + 2, 64), a3 = __shfl(idx, j + 3, 64);
            int a4 = __shfl(idx, j + 4, 64), a5 = __shfl(idx, j + 5, 64);
            int a6 = __shfl(idx, j + 6, 64), a7 = __shfl(idx, j + 7, 64);
            int n0 = half ? a1 : a0, n1 = half ? a3 : a2;
            int n2 = half ? a5 : a4, n3 = half ? a7 : a6;
            unsigned int u0 = xt[(size_t)n0 * 32 + col];
            unsigned int u1 = xt[(size_t)n1 * 32 + col];
            unsigned int u2 = xt[(size_t)n2 * 32 + col];
            unsigned int u3 = xt[(size_t)n3 * 32 + col];
            s0 += bf_lo(u0) + bf_lo(u1) + bf_lo(u2) + bf_lo(u3);
            s1 += bf_hi(u0) + bf_hi(u1) + bf_hi(u2) + bf_hi(u3);
        }
        for (; j + 2 <= cnt; j += 2) {
            int a0 = __shfl(idx, j, 64), a1 = __shfl(idx, j + 1, 64);
            int nb = half ? a1 : a0;
            unsigned int u = xt[(size_t)nb * 32 + col];
            s0 += bf_lo(u); s1 += bf_hi(u);
        }
        if (j < cnt) {
            int nb = __shfl(idx, j, 64);
            if (!half) {
                unsigned int u = xt[(size_t)nb * 32 + col];
                s0 += bf_lo(u); s1 += bf_hi(u);
            }
        }
        e += cnt;
    }

    // cross-half reduce
    s0 += __shfl(s0, lane ^ 32, 64);
    s1 += __shfl(s1, lane ^ 32, 64);

    if (!half) {
        float inv = 1.0f / fmaxf((float)(end - start), 1.0f);
        unsigned int ur = xt[(size_t)node * 32 + col];
        float2 o;
        o.x = s0 * inv + bf_lo(ur);
        o.y = s1 * inv + bf_hi(ur);
        *(float2*)&h[(size_t)node * 64 + col * 2] = o;
    }
}

// ---------------- Aggregation (bf16 table, F=128) ----------------

__global__ __launch_bounds__(256) void agg_bf16_128_kernel(const bf16* __restrict__ xb,
                                                           const int* __restrict__ offsets,
                                                           const int* __restrict__ csr_src,
                                                           float* __restrict__ h, int n) {
    const int lane = threadIdx.x & 63;
    const int node = blockIdx.x * 4 + (threadIdx.x >> 6);
    if (node >= n) return;
    const int start = offsets[node];
    const int end   = offsets[node + 1];
    const unsigned int* xt = (const unsigned int*)xb;   // row stride 64 uints

    float s0 = 0.f, s1 = 0.f;
    int e = start;
    while (e < end) {
        int cnt = min(64, end - e);
        int ii = e + lane; if (ii >= end) ii = end - 1;
        int idx = csr_src[ii];
        int j = 0;
        for (; j + 4 <= cnt; j += 4) {
            int n0 = __shfl(idx, j,     64);
            int n1 = __shfl(idx, j + 1, 64);
            int n2 = __shfl(idx, j + 2, 64);
            int n3 = __shfl(idx, j + 3, 64);
            unsigned int u0 = xt[(size_t)n0 * 64 + lane];
            unsigned int u1 = xt[(size_t)n1 * 64 + lane];
            unsigned int u2 = xt[(size_t)n2 * 64 + lane];
            unsigned int u3 = xt[(size_t)n3 * 64 + lane];
            s0 += bf_lo(u0) + bf_lo(u1) + bf_lo(u2) + bf_lo(u3);
            s1 += bf_hi(u0) + bf_hi(u1) + bf_hi(u2) + bf_hi(u3);
        }
        for (; j < cnt; ++j) {
            int nb = __shfl(idx, j, 64);
            unsigned int u = xt[(size_t)nb * 64 + lane];
            s0 += bf_lo(u); s1 += bf_hi(u);
        }
        e += cnt;
    }

    float inv = 1.0f / fmaxf((float)(end - start), 1.0f);
    unsigned int ur = xt[(size_t)node * 64 + lane];
    float2 o;
    o.x = s0 * inv + bf_lo(ur);
    o.y = s1 * inv + bf_hi(ur);
    *(float2*)&h[(size_t)node * 128 + lane * 2] = o;
}

// ---------------- Tiled GEMM: Y = act(H @ W^T + b), fp32 math, fp32 or bf16 out ----------------

template <int F_IN, int F_OUT, bool RELU, typename OUT_T>
__global__ __launch_bounds__(256) void gemm_kernel(const float* __restrict__ H,
                                                   const float* __restrict__ W,
                                                   const float* __restrict__ bias,
                                                   OUT_T* __restrict__ Y, int n) {
    constexpr int BK = 64, PAD = 68, MT = 64;
    constexpr int OJ = F_OUT / 16;
    __shared__ float Ws[F_OUT * PAD];
    __shared__ float Hs[MT * PAD];

    const int tid = threadIdx.x;
    const int tx = tid & 15, ty = tid >> 4;   // 16 x 16
    const int m0 = blockIdx.x * MT;
    const int mcnt = min(MT, n - m0);

    float acc[4][OJ];
#pragma unroll
    for (int i = 0; i < 4; ++i)
#pragma unroll
        for (int j = 0; j < OJ; ++j) acc[i][j] = 0.f;

    const int rt = tid >> 4;
    const int ct = (tid & 15) * 4;

    for (int kc = 0; kc < F_IN; kc += BK) {
        for (int r = rt; r < F_OUT; r += 16) {
            float4 v = *(const float4*)&W[(size_t)r * F_IN + kc + ct];
            *(float4*)&Ws[r * PAD + ct] = v;
        }
        for (int r = rt; r < MT; r += 16) {
            float4 v = make_float4(0.f, 0.f, 0.f, 0.f);
            if (r < mcnt) v = *(const float4*)&H[(size_t)(m0 + r) * F_IN + kc + ct];
            *(float4*)&Hs[r * PAD + ct] = v;
        }
        __syncthreads();

        for (int k = 0; k < BK; k += 4) {
            float4 hv[4], wv[OJ];
#pragma unroll
            for (int i = 0; i < 4; ++i) hv[i] = *(const float4*)&Hs[(ty + 16 * i) * PAD + k];
#pragma unroll
            for (int j = 0; j < OJ; ++j) wv[j] = *(const float4*)&Ws[(tx + 16 * j) * PAD + k];
#pragma unroll
            for (int i = 0; i < 4; ++i)
#pragma unroll
                for (int j = 0; j < OJ; ++j)
                    acc[i][j] += hv[i].x * wv[j].x + hv[i].y * wv[j].y
                               + hv[i].z * wv[j].z + hv[i].w * wv[j].w;
        }
        __syncthreads();
    }

#pragma unroll
    for (int i = 0; i < 4; ++i) {
        int m = ty + 16 * i;
        if (m < mcnt) {
#pragma unroll
            for (int j = 0; j < OJ; ++j) {
                int o = tx + 16 * j;
                float v = acc[i][j] + bias[o];
                if (RELU) v = fmaxf(v, 0.f);
                Y[(size_t)(m0 + m) * F_OUT + o] = (OUT_T)v;
            }
        }
    }
}

// ---------------- Heads: nev = X@Wp^T+bp (64), cls = X@Wc^T+bc (10) ----------------

__global__ __launch_bounds__(256) void heads_kernel(const float* __restrict__ X,
                                                    const float* __restrict__ Wp, const float* __restrict__ bp,
                                                    const float* __restrict__ Wc, const float* __restrict__ bc,
                                                    float* __restrict__ nev, float* __restrict__ cls, int n) {
    constexpr int PAD = 68, MT = 64, OJ = 5;   // 80 output rows (74 real, 6 zero)
    __shared__ float Ws[80 * PAD];
    __shared__ float Hs[MT * PAD];

    const int tid = threadIdx.x;
    const int rt = tid >> 4;
    const int ct = (tid & 15) * 4;
    const int m0 = blockIdx.x * MT;
    const int mcnt = min(MT, n - m0);

    for (int r = rt; r < 80; r += 16) {
        float4 v = make_float4(0.f, 0.f, 0.f, 0.f);
        if (r < 64)      v = *(const float4*)&Wp[(size_t)r * 64 + ct];
        else if (r < 74) v = *(const float4*)&Wc[(size_t)(r - 64) * 64 + ct];
        *(float4*)&Ws[r * PAD + ct] = v;
    }
    for (int r = rt; r < MT; r += 16) {
        float4 v = make_float4(0.f, 0.f, 0.f, 0.f);
        if (r < mcnt) v = *(const float4*)&X[(size_t)(m0 + r) * 64 + ct];
        *(float4*)&Hs[r * PAD + ct] = v;
    }
    __syncthreads();

    const int tx = tid & 15, ty = tid >> 4;
    float acc[4][OJ];
#pragma unroll
    for (int i = 0; i < 4; ++i)
#pragma unroll
        for (int j = 0; j < OJ; ++j) acc[i][j] = 0.f;

    for (int k = 0; k < 64; k += 4) {
        float4 hv[4], wv[OJ];
#pragma unroll
        for (int i = 0; i < 4; ++i) hv[i] = *(const float4*)&Hs[(ty + 16 * i) * PAD + k];
#pragma unroll
        for (int j = 0; j < OJ; ++j) wv[j] = *(const float4*)&Ws[(tx + 16 * j) * PAD + k];
#pragma unroll
        for (int i = 0; i < 4; ++i)
#pragma unroll
            for (int j = 0; j < OJ; ++j)
                acc[i][j] += hv[i].x * wv[j].x + hv[i].y * wv[j].y
                           + hv[i].z * wv[j].z + hv[i].w * wv[j].w;
    }

#pragma unroll
    for (int i = 0; i < 4; ++i) {
        int m = ty + 16 * i;
        if (m < mcnt) {
#pragma unroll
            for (int j = 0; j < OJ; ++j) {
                int o = tx + 16 * j;
                if (o < 64) {
                    nev[(size_t)(m0 + m) * 64 + o] = acc[i][j] + bp[o];
                } else if (o < 74) {
                    cls[(size_t)(m0 + m) * 10 + (o - 64)] = acc[i][j] + bc[o - 64];
                }
            }
        }
    }
}

// ---------------- launch ----------------

extern "C" void kernel_launch(void* const* d_in, const int* in_sizes, int n_in,
                              void* d_out, int out_size, void* d_ws, size_t ws_size,
                              hipStream_t stream) {
    const float* x  = (const float*)d_in[0];
    const int*   ei = (const int*)d_in[1];
    const float* W1 = (const float*)d_in[2];
    const float* b1 = (const float*)d_in[3];
    const float* W2 = (const float*)d_in[4];
    const float* b2 = (const float*)d_in[5];
    const float* W3 = (const float*)d_in[6];
    const float* b3 = (const float*)d_in[7];
    const float* Wp = (const float*)d_in[8];
    const float* bp = (const float*)d_in[9];
    const float* Wc = (const float*)d_in[10];
    const float* bc = (const float*)d_in[11];

    const int n = in_sizes[0] / 64;   // 50000
    const int E = in_sizes[1] / 2;    // 800000
    const int* src = ei;
    const int* dst = ei + E;

    const int nScanBlocks = (n + 255) / 256;   // 196

    // workspace layout
    int* deg      = (int*)d_ws;             // n
    int* offsets  = deg + n;                // n+1
    int* cursor   = offsets + (n + 1);      // n
    int* partial  = cursor + n;             // 256
    int* blockoff = partial + 256;          // 256
    int* csr_src  = blockoff + 256;         // E
    uintptr_t p = (uintptr_t)(csr_src + E);
    p = (p + 255) & ~(uintptr_t)255;
    float* Hbuf = (float*)p;                            // n*128 fp32 (agg out / gemm in)
    bf16*  Yb   = (bf16*)(Hbuf + (size_t)n * 128);      // n*128 bf16 (gemm out / gather table)
    unsigned int* xb = (unsigned int*)(Yb + (size_t)n * 128);  // n*32 uints (x as bf16)

    float* out_emb = (float*)d_out;                // n*64
    float* out_nev = out_emb + (size_t)n * 64;     // n*64
    float* out_cls = out_nev + (size_t)n * 64;     // n*10

    hipMemsetAsync(deg, 0, (size_t)n * sizeof(int), stream);

    convert_x_kernel<<<(n * 32 + 255) / 256, 256, 0, stream>>>(x, xb, n * 32);

    const int nSub = 96;   // 8 shards x 96 = 768 blocks (~3/CU)
    count_deg_sharded_kernel<<<8 * nSub, 256, 0, stream>>>(dst, deg, E, nSub);
    partial_sum_kernel<<<nScanBlocks, 256, 0, stream>>>(deg, partial, n);
    scan_partials_kernel<<<1, 256, 0, stream>>>(partial, blockoff, offsets, nScanBlocks, n);
    local_scan_kernel<<<nScanBlocks, 256, 0, stream>>>(deg, blockoff, offsets, cursor, n);
    scatter_sharded_kernel<<<8 * nSub, 256, 0, stream>>>(src, dst, cursor, csr_src, E, nSub);

    const int gAgg  = (n + 3) / 4;
    const int gGemm = (n + 63) / 64;

    agg_bf16_64_kernel<<<gAgg, 256, 0, stream>>>(xb, offsets, csr_src, Hbuf, n);
    gemm_kernel<64, 128, true, bf16><<<gGemm, 256, 0, stream>>>(Hbuf, W1, b1, Yb, n);

    agg_bf16_128_kernel<<<gAgg, 256, 0, stream>>>(Yb, offsets, csr_src, Hbuf, n);
    gemm_kernel<128, 128, true, bf16><<<gGemm, 256, 0, stream>>>(Hbuf, W2, b2, Yb, n);

    agg_bf16_128_kernel<<<gAgg, 256, 0, stream>>>(Yb, offsets, csr_src, Hbuf, n);
    gemm_kernel<128, 64, true, float><<<gGemm, 256, 0, stream>>>(Hbuf, W3, b3, out_emb, n);

    heads_kernel<<<gGemm, 256, 0, stream>>>(out_emb, Wp, bp, Wc, bc, out_nev, out_cls, n);
}

// Round 7
// 338.059 us; speedup vs baseline: 3.6772x; 1.0941x over previous
//
#include <hip/hip_runtime.h>
#include <hip/hip_bf16.h>

typedef __hip_bfloat16 bf16;
typedef __attribute__((ext_vector_type(8))) short short8;
typedef __attribute__((ext_vector_type(4))) float floatx4;

__device__ __forceinline__ float bf_lo(unsigned int u) { return __uint_as_float(u << 16); }
__device__ __forceinline__ float bf_hi(unsigned int u) { return __uint_as_float(u & 0xffff0000u); }

__device__ __forceinline__ unsigned short f2bf_rne(float f) {
    unsigned u = __float_as_uint(f);
    unsigned rb = (u >> 16) & 1u;
    u += 0x7fffu + rb;
    return (unsigned short)(u >> 16);
}
__device__ __forceinline__ unsigned int pack_bf2(float x, float y) {
    return (unsigned int)f2bf_rne(x) | ((unsigned int)f2bf_rne(y) << 16);
}

// ---------------- fp32 -> bf16 converts ----------------

__global__ __launch_bounds__(256) void convert_pairs_kernel(const float* __restrict__ x,
                                                            unsigned int* __restrict__ xb, int total) {
    int i = blockIdx.x * blockDim.x + threadIdx.x;   // one uint = 2 floats
    if (i < total) {
        float2 f = ((const float2*)x)[i];
        xb[i] = pack_bf2(f.x, f.y);
    }
}

// Pack heads weights: rows 0-63 Wp, 64-73 Wc, 74-79 zero; biases likewise.
__global__ __launch_bounds__(256) void heads_pack_kernel(const float* __restrict__ Wp, const float* __restrict__ bp,
                                                         const float* __restrict__ Wc, const float* __restrict__ bc,
                                                         unsigned short* __restrict__ Whb, float* __restrict__ hbias) {
    int i = blockIdx.x * blockDim.x + threadIdx.x;   // 80*64 = 5120
    if (i < 80 * 64) {
        int r = i >> 6, c = i & 63;
        float v = 0.f;
        if (r < 64) v = Wp[r * 64 + c];
        else if (r < 74) v = Wc[(r - 64) * 64 + c];
        Whb[i] = f2bf_rne(v);
    }
    if (i < 80) {
        float v = 0.f;
        if (i < 64) v = bp[i];
        else if (i < 74) v = bc[i - 64];
        hbias[i] = v;
    }
}

// ---------------- CSR build (XCD-sharded by dst>>8 & 7) ----------------

__global__ __launch_bounds__(256) void count_deg_sharded_kernel(const int* __restrict__ dst,
                                                                int* __restrict__ deg, int E, int nSub) {
    const int shard = blockIdx.x & 7;
    const int sub   = blockIdx.x >> 3;
    const int per   = (E + nSub - 1) / nSub;
    const int lo = sub * per;
    const int hi = min(lo + per, E);
    for (int e = lo + threadIdx.x; e < hi; e += 256) {
        int d = dst[e];
        if (((d >> 8) & 7) == shard) atomicAdd(&deg[d], 1);
    }
}

__global__ __launch_bounds__(256) void scatter_sharded_kernel(const int* __restrict__ src,
                                                              const int* __restrict__ dst,
                                                              int* __restrict__ cursor,
                                                              int* __restrict__ csr_src, int E, int nSub) {
    const int shard = blockIdx.x & 7;
    const int sub   = blockIdx.x >> 3;
    const int per   = (E + nSub - 1) / nSub;
    const int lo = sub * per;
    const int hi = min(lo + per, E);
    for (int e = lo + threadIdx.x; e < hi; e += 256) {
        int d = dst[e];
        if (((d >> 8) & 7) == shard) {
            int s = src[e];
            int pos = atomicAdd(&cursor[d], 1);
            csr_src[pos] = s;
        }
    }
}

// Two-level scan, 256 elements per block.
__global__ __launch_bounds__(256) void partial_sum_kernel(const int* __restrict__ deg,
                                                          int* __restrict__ partial, int n) {
    __shared__ int s[256];
    int t = threadIdx.x;
    int i = blockIdx.x * 256 + t;
    s[t] = (i < n) ? deg[i] : 0;
    __syncthreads();
    for (int off = 128; off > 0; off >>= 1) {
        if (t < off) s[t] += s[t + off];
        __syncthreads();
    }
    if (t == 0) partial[blockIdx.x] = s[0];
}

__global__ __launch_bounds__(256) void scan_partials_kernel(const int* __restrict__ partial,
                                                            int* __restrict__ blockoff,
                                                            int* __restrict__ offsets,
                                                            int nblocks, int n) {
    __shared__ int s[256];
    int t = threadIdx.x;
    int v = (t < nblocks) ? partial[t] : 0;
    s[t] = v;
    __syncthreads();
    for (int off = 1; off < 256; off <<= 1) {
        int u = (t >= off) ? s[t - off] : 0;
        __syncthreads();
        s[t] += u;
        __syncthreads();
    }
    if (t < nblocks) blockoff[t] = s[t] - v;   // exclusive
    if (t == nblocks - 1) offsets[n] = s[t];   // total
}

__global__ __launch_bounds__(256) void local_scan_kernel(const int* __restrict__ deg,
                                                         const int* __restrict__ blockoff,
                                                         int* __restrict__ offsets,
                                                         int* __restrict__ cursor, int n) {
    __shared__ int s[256];
    int t = threadIdx.x;
    int i = blockIdx.x * 256 + t;
    int v = (i < n) ? deg[i] : 0;
    s[t] = v;
    __syncthreads();
    for (int off = 1; off < 256; off <<= 1) {
        int u = (t >= off) ? s[t - off] : 0;
        __syncthreads();
        s[t] += u;
        __syncthreads();
    }
    if (i < n) {
        int o = blockoff[blockIdx.x] + s[t] - v;  // exclusive prefix
        offsets[i] = o;
        cursor[i]  = o;
    }
}

// ---------------- Aggregation (bf16 table, F=64): h = mean-neighbor + self ----------------
// Wave per node; half-wave per neighbor. Output bf16 (row = 32 uints).

__global__ __launch_bounds__(256) void agg_bf16_64_kernel(const unsigned int* __restrict__ xt,
                                                          const int* __restrict__ offsets,
                                                          const int* __restrict__ csr_src,
                                                          unsigned int* __restrict__ hb, int n) {
    const int lane = threadIdx.x & 63;
    const int node = blockIdx.x * 4 + (threadIdx.x >> 6);
    if (node >= n) return;
    const int half = lane >> 5;
    const int col  = lane & 31;          // uint column (2 features)
    const int start = offsets[node];
    const int end   = offsets[node + 1];

    float s0 = 0.f, s1 = 0.f;
    int e = start;
    while (e < end) {
        int cnt = min(64, end - e);
        int ii = e + lane; if (ii >= end) ii = end - 1;
        int idx = csr_src[ii];
        int j = 0;
        for (; j + 8 <= cnt; j += 8) {
            int a0 = __shfl(idx, j + 0, 64), a1 = __shfl(idx, j + 1, 64);
            int a2 = __shfl(idx, j + 2, 64), a3 = __shfl(idx, j + 3, 64);
            int a4 = __shfl(idx, j + 4, 64), a5 = __shfl(idx, j + 5, 64);
            int a6 = __shfl(idx, j + 6, 64), a7 = __shfl(idx, j + 7, 64);
            int n0 = half ? a1 : a0, n1 = half ? a3 : a2;
            int n2 = half ? a5 : a4, n3 = half ? a7 : a6;
            unsigned int u0 = xt[(size_t)n0 * 32 + col];
            unsigned int u1 = xt[(size_t)n1 * 32 + col];
            unsigned int u2 = xt[(size_t)n2 * 32 + col];
            unsigned int u3 = xt[(size_t)n3 * 32 + col];
            s0 += bf_lo(u0) + bf_lo(u1) + bf_lo(u2) + bf_lo(u3);
            s1 += bf_hi(u0) + bf_hi(u1) + bf_hi(u2) + bf_hi(u3);
        }
        for (; j + 2 <= cnt; j += 2) {
            int a0 = __shfl(idx, j, 64), a1 = __shfl(idx, j + 1, 64);
            int nb = half ? a1 : a0;
            unsigned int u = xt[(size_t)nb * 32 + col];
            s0 += bf_lo(u); s1 += bf_hi(u);
        }
        if (j < cnt) {
            int nb = __shfl(idx, j, 64);
            if (!half) {
                unsigned int u = xt[(size_t)nb * 32 + col];
                s0 += bf_lo(u); s1 += bf_hi(u);
            }
        }
        e += cnt;
    }

    s0 += __shfl(s0, lane ^ 32, 64);
    s1 += __shfl(s1, lane ^ 32, 64);

    if (!half) {
        float inv = 1.0f / fmaxf((float)(end - start), 1.0f);
        unsigned int ur = xt[(size_t)node * 32 + col];
        hb[(size_t)node * 32 + col] = pack_bf2(s0 * inv + bf_lo(ur), s1 * inv + bf_hi(ur));
    }
}

// ---------------- Aggregation (bf16 table, F=128), bf16 out (row = 64 uints) ----------------

__global__ __launch_bounds__(256) void agg_bf16_128_kernel(const unsigned int* __restrict__ xt,
                                                           const int* __restrict__ offsets,
                                                           const int* __restrict__ csr_src,
                                                           unsigned int* __restrict__ hb, int n) {
    const int lane = threadIdx.x & 63;
    const int node = blockIdx.x * 4 + (threadIdx.x >> 6);
    if (node >= n) return;
    const int start = offsets[node];
    const int end   = offsets[node + 1];

    float s0 = 0.f, s1 = 0.f;
    int e = start;
    while (e < end) {
        int cnt = min(64, end - e);
        int ii = e + lane; if (ii >= end) ii = end - 1;
        int idx = csr_src[ii];
        int j = 0;
        for (; j + 4 <= cnt; j += 4) {
            int n0 = __shfl(idx, j,     64);
            int n1 = __shfl(idx, j + 1, 64);
            int n2 = __shfl(idx, j + 2, 64);
            int n3 = __shfl(idx, j + 3, 64);
            unsigned int u0 = xt[(size_t)n0 * 64 + lane];
            unsigned int u1 = xt[(size_t)n1 * 64 + lane];
            unsigned int u2 = xt[(size_t)n2 * 64 + lane];
            unsigned int u3 = xt[(size_t)n3 * 64 + lane];
            s0 += bf_lo(u0) + bf_lo(u1) + bf_lo(u2) + bf_lo(u3);
            s1 += bf_hi(u0) + bf_hi(u1) + bf_hi(u2) + bf_hi(u3);
        }
        for (; j < cnt; ++j) {
            int nb = __shfl(idx, j, 64);
            unsigned int u = xt[(size_t)nb * 64 + lane];
            s0 += bf_lo(u); s1 += bf_hi(u);
        }
        e += cnt;
    }

    float inv = 1.0f / fmaxf((float)(end - start), 1.0f);
    unsigned int ur = xt[(size_t)node * 64 + lane];
    hb[(size_t)node * 64 + lane] = pack_bf2(s0 * inv + bf_lo(ur), s1 * inv + bf_hi(ur));
}

// ---------------- MFMA GEMM: Y = act(H @ W^T + b), bf16 in, fp32 accum ----------------
// 256 thr = 4 waves; 64 rows/block; no LDS. A/B frags per verified 16x16x32 layout:
// A[m=lane&15][k=quad*8+j], B row (lane&15) of W; C/D: col=lane&15, row=quad*4+reg.
// MODE 0: bf16 out + relu. MODE 1: fp32 out + bf16 copy + relu (layer 3).
// MODE 2: heads — split store nev (o<64) / cls (64<=o<74), no relu.

template <int F_IN, int F_OUT, int MODE>
__global__ __launch_bounds__(256) void mfma_gemm_kernel(const unsigned short* __restrict__ Hb,
                                                        const unsigned short* __restrict__ Wb,
                                                        const float* __restrict__ bias,
                                                        unsigned short* __restrict__ Yb,
                                                        float* __restrict__ Yf,
                                                        float* __restrict__ cls, int n) {
    constexpr int KC = F_IN / 32;
    constexpr int NJ = F_OUT / 16;
    const int lane = threadIdx.x & 63;
    const int wv   = threadIdx.x >> 6;
    const int quad = lane >> 4;
    const int r16  = lane & 15;
    const int m0   = blockIdx.x * 64 + wv * 16;

    short8 a[KC];
    const int am = m0 + r16;
    if (am < n) {
#pragma unroll
        for (int c = 0; c < KC; ++c)
            a[c] = *(const short8*)&Hb[(size_t)am * F_IN + 32 * c + quad * 8];
    } else {
#pragma unroll
        for (int c = 0; c < KC; ++c)
#pragma unroll
            for (int i = 0; i < 8; ++i) a[c][i] = 0;
    }

    floatx4 acc[NJ];
#pragma unroll
    for (int j = 0; j < NJ; ++j)
#pragma unroll
        for (int r = 0; r < 4; ++r) acc[j][r] = 0.f;

#pragma unroll
    for (int j = 0; j < NJ; ++j) {
#pragma unroll
        for (int c = 0; c < KC; ++c) {
            short8 b = *(const short8*)&Wb[(size_t)(16 * j + r16) * F_IN + 32 * c + quad * 8];
            acc[j] = __builtin_amdgcn_mfma_f32_16x16x32_bf16(a[c], b, acc[j], 0, 0, 0);
        }
    }

#pragma unroll
    for (int r = 0; r < 4; ++r) {
        const int mm = m0 + quad * 4 + r;
        if (mm >= n) continue;
#pragma unroll
        for (int j = 0; j < NJ; ++j) {
            const int o = 16 * j + r16;
            float v = acc[j][r] + bias[o];
            if (MODE == 0) {
                v = fmaxf(v, 0.f);
                Yb[(size_t)mm * F_OUT + o] = f2bf_rne(v);
            } else if (MODE == 1) {
                v = fmaxf(v, 0.f);
                Yf[(size_t)mm * F_OUT + o] = v;
                Yb[(size_t)mm * F_OUT + o] = f2bf_rne(v);
            } else {
                if (o < 64)      Yf[(size_t)mm * 64 + o] = v;
                else if (o < 74) cls[(size_t)mm * 10 + (o - 64)] = v;
            }
        }
    }
}

// ---------------- launch ----------------

extern "C" void kernel_launch(void* const* d_in, const int* in_sizes, int n_in,
                              void* d_out, int out_size, void* d_ws, size_t ws_size,
                              hipStream_t stream) {
    const float* x  = (const float*)d_in[0];
    const int*   ei = (const int*)d_in[1];
    const float* W1 = (const float*)d_in[2];
    const float* b1 = (const float*)d_in[3];
    const float* W2 = (const float*)d_in[4];
    const float* b2 = (const float*)d_in[5];
    const float* W3 = (const float*)d_in[6];
    const float* b3 = (const float*)d_in[7];
    const float* Wp = (const float*)d_in[8];
    const float* bp = (const float*)d_in[9];
    const float* Wc = (const float*)d_in[10];
    const float* bc = (const float*)d_in[11];

    const int n = in_sizes[0] / 64;   // 50000
    const int E = in_sizes[1] / 2;    // 800000
    const int* src = ei;
    const int* dst = ei + E;

    const int nScanBlocks = (n + 255) / 256;   // 196

    // workspace layout
    int* deg      = (int*)d_ws;             // n
    int* offsets  = deg + n;                // n+1
    int* cursor   = offsets + (n + 1);      // n
    int* partial  = cursor + n;             // 256
    int* blockoff = partial + 256;          // 256
    int* csr_src  = blockoff + 256;         // E
    uintptr_t p = (uintptr_t)(csr_src + E);
    p = (p + 255) & ~(uintptr_t)255;
    unsigned int* Hb = (unsigned int*)p;           // n*64 uints (<=128 bf16/row)
    unsigned int* Yb = Hb + (size_t)n * 64;        // n*64 uints
    unsigned int* xb = Yb + (size_t)n * 64;        // n*32 uints (x bf16)
    unsigned int* Xb3 = xb + (size_t)n * 32;       // n*32 uints (emb bf16)
    unsigned short* W1b = (unsigned short*)(Xb3 + (size_t)n * 32);  // 128*64
    unsigned short* W2b = W1b + 128 * 64;          // 128*128
    unsigned short* W3b = W2b + 128 * 128;         // 64*128
    unsigned short* Whb = W3b + 64 * 128;          // 80*64
    float* hbias = (float*)(Whb + 80 * 64);        // 80

    float* out_emb = (float*)d_out;                // n*64
    float* out_nev = out_emb + (size_t)n * 64;     // n*64
    float* out_cls = out_nev + (size_t)n * 64;     // n*10

    hipMemsetAsync(deg, 0, (size_t)n * sizeof(int), stream);

    convert_pairs_kernel<<<(n * 32 + 255) / 256, 256, 0, stream>>>(x, xb, n * 32);
    convert_pairs_kernel<<<(128 * 32 + 255) / 256, 256, 0, stream>>>(W1, (unsigned int*)W1b, 128 * 32);
    convert_pairs_kernel<<<(128 * 64 + 255) / 256, 256, 0, stream>>>(W2, (unsigned int*)W2b, 128 * 64);
    convert_pairs_kernel<<<(64 * 64 + 255) / 256, 256, 0, stream>>>(W3, (unsigned int*)W3b, 64 * 64);
    heads_pack_kernel<<<(80 * 64 + 255) / 256, 256, 0, stream>>>(Wp, bp, Wc, bc, Whb, hbias);

    const int nSub = 96;   // 8 shards x 96 = 768 blocks
    count_deg_sharded_kernel<<<8 * nSub, 256, 0, stream>>>(dst, deg, E, nSub);
    partial_sum_kernel<<<nScanBlocks, 256, 0, stream>>>(deg, partial, n);
    scan_partials_kernel<<<1, 256, 0, stream>>>(partial, blockoff, offsets, nScanBlocks, n);
    local_scan_kernel<<<nScanBlocks, 256, 0, stream>>>(deg, blockoff, offsets, cursor, n);
    scatter_sharded_kernel<<<8 * nSub, 256, 0, stream>>>(src, dst, cursor, csr_src, E, nSub);

    const int gAgg  = (n + 3) / 4;
    const int gMf   = (n + 63) / 64;

    agg_bf16_64_kernel<<<gAgg, 256, 0, stream>>>(xb, offsets, csr_src, Hb, n);
    mfma_gemm_kernel<64, 128, 0><<<gMf, 256, 0, stream>>>((const unsigned short*)Hb, W1b, b1,
                                                          (unsigned short*)Yb, nullptr, nullptr, n);

    agg_bf16_128_kernel<<<gAgg, 256, 0, stream>>>(Yb, offsets, csr_src, Hb, n);
    mfma_gemm_kernel<128, 128, 0><<<gMf, 256, 0, stream>>>((const unsigned short*)Hb, W2b, b2,
                                                           (unsigned short*)Yb, nullptr, nullptr, n);

    agg_bf16_128_kernel<<<gAgg, 256, 0, stream>>>(Yb, offsets, csr_src, Hb, n);
    mfma_gemm_kernel<128, 64, 1><<<gMf, 256, 0, stream>>>((const unsigned short*)Hb, W3b, b3,
                                                          (unsigned short*)Xb3, out_emb, nullptr, n);

    mfma_gemm_kernel<64, 80, 2><<<gMf, 256, 0, stream>>>((const unsigned short*)Xb3, Whb, hbias,
                                                         nullptr, out_nev, out_cls, n);
}